// Round 23
// baseline (66.502 us; speedup 1.0000x reference)
//
#include <hip/hip_runtime.h>

// Problem constants: B=8, N=2048, M=2048, D=128
#define B_DIM 8
#define N_DIM 2048
#define M_DIM 2048
#define D_DIM 128
#define NT_TILES 4          // tiles of 128 cols per block

typedef __bf16 bf16_t;
typedef bf16_t bf16x8 __attribute__((ext_vector_type(8)));
typedef float f32x4 __attribute__((ext_vector_type(4)));
typedef float f32x16 __attribute__((ext_vector_type(16)));

// lgkm-only barrier: never drains vmcnt -> global stores / prefetch loads
// stay in flight across tile boundaries.
__device__ __forceinline__ void lgkm_barrier() {
    asm volatile("s_waitcnt lgkmcnt(0)" ::: "memory");
    __builtin_amdgcn_s_barrier();
}

// ---------------------------------------------------------------------------
// R15 champion body (32x32x16 MFMA, full-line NONTEMPORAL stores, fused
// staging, XCD-batch swizzle, lgkm-only barriers, prefetch-before-stores)
// at 512 THREADS/BLOCK for 16 WAVES/CU:
//
// R16 established: achieved write BW ~ linear in resident waves/CU
// (4 waves ~1.6 TB/s, 8 waves ~3.5-4 TB/s; each wave sustains a bounded
// number of in-flight stores). R17's attempt (3 smaller blocks) failed
// because launch_bounds(256,3) made the compiler target 84 VGPR -> rematof
// the A fragments, and halved barrier amortization.
//
// This version keeps the champion's LDS (66.5KB) and tile cadence but uses
// 512-thread blocks: 2 blocks/CU (LDS-bound) = 16 waves/CU, double the
// champion. launch_bounds(512,4) pins the VGPR cap at exactly 128 (the
// champion's working allocation). Per-wave state halves to fit: 8 waves in
// 2x4 layout, each owns 64 rows x 32 cols (af 32 + acc 32 + prefetch 32
// VGPR). Barrier count per byte written is unchanged.
// ---------------------------------------------------------------------------
__global__ __launch_bounds__(512, 4) void fused_dist_kernel(
    const float* __restrict__ L, const float* __restrict__ R,
    float* __restrict__ out)
{
    __shared__ bf16x8 Als[2048];   // 32 KB: A panel, 8 groups x 256 granules
    __shared__ bf16x8 Bls[2048];   // 32 KB: B tile (128 rows)
    __shared__ float nAs[128];
    __shared__ float nBs[128];

    // ---- XCD-locality decode: one batch per XCD (blockIdx round-robins XCDs)
    const int w   = blockIdx.x;    // [0, 512)
    const int bz  = w & 7;         // XCD id == batch
    const int i   = w >> 3;        // [0, 64) within XCD
    const int bxg = i & 3;         // covers NT_TILES tiles of 128 cols
    const int by  = i >> 2;        // [0, 16)

    const int tid  = threadIdx.x;
    const int wid  = tid >> 6;         // 0..7
    const int lane = tid & 63;
    const int rA   = lane & 15;        // row within 16-row LDS group
    const int g2   = (lane >> 4) & 1;  // which 16-row group within 32
    const int hi   = lane >> 5;        // 0..1 (K-half / row-offset select)
    const int c32  = lane & 31;        // fragment row/col within 32
    const int gran = tid & 15;         // staging: 8-elem chunk
    const int rsl  = tid >> 4;         // staging: row slot 0..31

    const float* Asrc = L + ((size_t)bz * N_DIM + (size_t)by * 128) * D_DIM;
    const float* Rbat = R + (size_t)bz * M_DIM * D_DIM;

    // ---- initial stage: A panel (bf16 RNE + norms from SAME rounded values)
    #pragma unroll
    for (int i2 = 0; i2 < 4; ++i2) {
        int row = i2 * 32 + rsl;
        float4 v0 = ((const float4*)Asrc)[(size_t)row * 32 + gran * 2];
        float4 v1 = ((const float4*)Asrc)[(size_t)row * 32 + gran * 2 + 1];
        bf16x8 p = { (bf16_t)v0.x, (bf16_t)v0.y, (bf16_t)v0.z, (bf16_t)v0.w,
                     (bf16_t)v1.x, (bf16_t)v1.y, (bf16_t)v1.z, (bf16_t)v1.w };
        Als[(row >> 4) * 256 + gran * 16 + ((row & 15) ^ gran)] = p;
        float s = 0.0f;
        #pragma unroll
        for (int j = 0; j < 8; ++j) { float x = (float)p[j]; s = fmaf(x, x, s); }
        s += __shfl_xor(s, 1); s += __shfl_xor(s, 2);
        s += __shfl_xor(s, 4); s += __shfl_xor(s, 8);
        if (gran == 0) nAs[row] = s;
    }
    // ---- initial stage: B tile 0 (128 rows)
    {
        const float* Bsrc = Rbat + (size_t)(bxg * NT_TILES) * 128 * D_DIM;
        #pragma unroll
        for (int i2 = 0; i2 < 4; ++i2) {
            int row = i2 * 32 + rsl;
            float4 v0 = ((const float4*)Bsrc)[(size_t)row * 32 + gran * 2];
            float4 v1 = ((const float4*)Bsrc)[(size_t)row * 32 + gran * 2 + 1];
            bf16x8 p = { (bf16_t)v0.x, (bf16_t)v0.y, (bf16_t)v0.z, (bf16_t)v0.w,
                         (bf16_t)v1.x, (bf16_t)v1.y, (bf16_t)v1.z, (bf16_t)v1.w };
            Bls[(row >> 4) * 256 + gran * 16 + ((row & 15) ^ gran)] = p;
            float s = 0.0f;
            #pragma unroll
            for (int j = 0; j < 8; ++j) { float x = (float)p[j]; s = fmaf(x, x, s); }
            s += __shfl_xor(s, 1); s += __shfl_xor(s, 2);
            s += __shfl_xor(s, 4); s += __shfl_xor(s, 8);
            if (gran == 0) nBs[row] = s;
        }
    }
    lgkm_barrier();

    // ---- wave tile bases: 8 waves in 2x4; wave owns 64 rows x 32 cols
    const int wr = wid >> 2;           // 0..1
    const int wc = wid & 3;            // 0..3
    const int wM = wr * 64;
    const int wN = wc * 32;

    // ---- A fragments into registers (Als dead afterwards): af[tm][s]
    bf16x8 af[2][8];
    #pragma unroll
    for (int s = 0; s < 8; ++s) {
        const int gr = s * 2 + hi;           // 16B k-granule
        #pragma unroll
        for (int tm = 0; tm < 2; ++tm) {
            const int grp = wr * 4 + tm * 2 + g2;
            af[tm][s] = Als[grp * 256 + gr * 16 + (rA ^ gr)];
        }
    }

    // ---- tile loop (4 tiles of 128 cols)
    for (int t = 0; t < NT_TILES; ++t) {
        const int bx = bxg * NT_TILES + t;

        // 1. MFMA on current B tile (8 K-steps of 16, 2 indep chains)
        f32x16 acc[2] = {};
        #pragma unroll
        for (int s = 0; s < 8; ++s) {
            const int gr = s * 2 + hi;
            const bf16x8 bfr = Bls[(wc * 2 + g2) * 256 + gr * 16 + (rA ^ gr)];
            acc[0] = __builtin_amdgcn_mfma_f32_32x32x16_bf16(
                af[0][s], bfr, acc[0], 0, 0, 0);
            acc[1] = __builtin_amdgcn_mfma_f32_32x32x16_bf16(
                af[1][s], bfr, acc[1], 0, 0, 0);
        }

        // 2. prefetch next B tile (f32) into regs BEFORE any stores issue
        //    (vmcnt retires in-order: restage's wait stays counted, stores
        //     never force-drained)
        float4 pf0[4], pf1[4];
        if (t + 1 < NT_TILES) {
            const float* Bsrc = Rbat + (size_t)(bx + 1) * 128 * D_DIM;
            #pragma unroll
            for (int i2 = 0; i2 < 4; ++i2) {
                int row = i2 * 32 + rsl;
                pf0[i2] = ((const float4*)Bsrc)[(size_t)row * 32 + gran * 2];
                pf1[i2] = ((const float4*)Bsrc)[(size_t)row * 32 + gran * 2 + 1];
            }
        }

        // 3. epilogue + full-line NONTEMPORAL stores
        //    out-row = wM + tm*32 + g*8 + hi*4 + e,  out-col = bx*128 + wN + c32
        const size_t outBase =
            ((size_t)bz * N_DIM + (size_t)by * 128) * M_DIM + (size_t)bx * 128;
        const int col_l = wN + c32;
        const float r2 = nBs[col_l];
        float* ocol = out + outBase + col_l;
        #pragma unroll
        for (int tm = 0; tm < 2; ++tm) {
            #pragma unroll
            for (int g = 0; g < 4; ++g) {
                const int rowb = wM + tm * 32 + g * 8 + hi * 4;
                const f32x4 l2q = *(const f32x4*)&nAs[rowb];
                #pragma unroll
                for (int e = 0; e < 4; ++e) {
                    float d2 = fmaf(-2.0f, acc[tm][g * 4 + e], l2q[e] + r2);
                    d2 = fmaxf(d2, 0.0f);
                    float sq = __builtin_amdgcn_sqrtf(d2);
                    float o = __builtin_amdgcn_rcpf(1.0f + sq);
                    __builtin_nontemporal_store(
                        o, ocol + (size_t)(rowb + e) * M_DIM);
                }
            }
        }

        // 4. restage next B tile from prefetched regs (lgkm-only barriers)
        if (t + 1 < NT_TILES) {
            lgkm_barrier();                    // all waves done reading Bls/nBs
            #pragma unroll
            for (int i2 = 0; i2 < 4; ++i2) {
                int row = i2 * 32 + rsl;
                bf16x8 p = { (bf16_t)pf0[i2].x, (bf16_t)pf0[i2].y,
                             (bf16_t)pf0[i2].z, (bf16_t)pf0[i2].w,
                             (bf16_t)pf1[i2].x, (bf16_t)pf1[i2].y,
                             (bf16_t)pf1[i2].z, (bf16_t)pf1[i2].w };
                Bls[(row >> 4) * 256 + gran * 16 + ((row & 15) ^ gran)] = p;
                float s = 0.0f;
                #pragma unroll
                for (int j = 0; j < 8; ++j) { float x = (float)p[j]; s = fmaf(x, x, s); }
                s += __shfl_xor(s, 1); s += __shfl_xor(s, 2);
                s += __shfl_xor(s, 4); s += __shfl_xor(s, 8);
                if (gran == 0) nBs[row] = s;
            }
            lgkm_barrier();                    // staging visible
        }
    }
}

extern "C" void kernel_launch(void* const* d_in, const int* in_sizes, int n_in,
                              void* d_out, int out_size, void* d_ws, size_t ws_size,
                              hipStream_t stream) {
    const float* L = (const float*)d_in[0];
    const float* R = (const float*)d_in[1];
    float* out = (float*)d_out;

    // 1D grid: w&7 selects XCD (round-robin) == batch; 64 blocks per XCD.
    dim3 grid(512, 1, 1);
    dim3 block(512);
    fused_dist_kernel<<<grid, block, 0, stream>>>(L, R, out);
}

// Round 24
// 33.209 us; speedup vs baseline: 2.0025x; 2.0025x over previous
//
#include <hip/hip_runtime.h>

// Problem constants: B=8, N=2048, M=2048, D=128
#define B_DIM 8
#define N_DIM 2048
#define M_DIM 2048
#define D_DIM 128
#define NT_TILES 8          // tiles of 64 cols per block

typedef __bf16 bf16_t;
typedef bf16_t bf16x8 __attribute__((ext_vector_type(8)));
typedef float f32x4 __attribute__((ext_vector_type(4)));
typedef float f32x16 __attribute__((ext_vector_type(16)));

// lgkm-only barrier: never drains vmcnt -> global stores / prefetch loads
// stay in flight across tile boundaries.
__device__ __forceinline__ void lgkm_barrier() {
    asm volatile("s_waitcnt lgkmcnt(0)" ::: "memory");
    __builtin_amdgcn_s_barrier();
}

// ---------------------------------------------------------------------------
// Champion body (32x32x16 MFMA, full-line NONTEMPORAL stores, fused staging,
// XCD-batch swizzle, lgkm-only barriers, prefetch-before-stores) at
// 12 WAVES/CU -- THE CLEAN WAVE-SCALING TEST:
//
// R16: write BW ~ linear in resident waves (4w ~1.5 TB/s, 8w ~4 TB/s).
// R17 (256,3 -> 84 VGPR) and R18 (512,4 -> 64 VGPR) were invalidated by the
// compiler allocating below the kernel's resident state (remat + spills).
// This version: B tile shrunk to 64 rows (16KB) => LDS = 32A + 16B + norms
// ~= 49KB => 3 blocks/CU = 12 waves, and NO min-waves launch bound: the
// compiler allocates ~150 VGPR freely, which is under the 168 cap for
// 3 waves/SIMD -- both constraints land on 3 blocks/CU without remat.
// Wave owns 64 rows x 32 cols (af 64 + acc 32 + pf 32 VGPR). NT_TILES=8
// keeps output-per-block identical to the champion (128x512).
// ---------------------------------------------------------------------------
__global__ __launch_bounds__(256) void fused_dist_kernel(
    const float* __restrict__ L, const float* __restrict__ R,
    float* __restrict__ out)
{
    __shared__ bf16x8 Als[2048];   // 32 KB: A panel, 8 groups x 256 granules
    __shared__ bf16x8 Bls[1024];   // 16 KB: B tile, 4 groups (64 rows)
    __shared__ float nAs[128];
    __shared__ float nBs[64];

    // ---- XCD-locality decode: one batch per XCD (blockIdx round-robins XCDs)
    const int w   = blockIdx.x;    // [0, 512)
    const int bz  = w & 7;         // XCD id == batch
    const int i   = w >> 3;        // [0, 64) within XCD
    const int bxg = i & 3;         // covers NT_TILES tiles of 64 cols
    const int by  = i >> 2;        // [0, 16)

    const int tid  = threadIdx.x;
    const int wid  = tid >> 6;         // 0..3
    const int lane = tid & 63;
    const int rA   = lane & 15;        // row within 16-row LDS group
    const int g2   = (lane >> 4) & 1;  // which 16-row group within 32
    const int hi   = lane >> 5;        // 0..1 (K-half / row-offset select)
    const int c32  = lane & 31;        // fragment row/col within 32
    const int r    = tid >> 4;         // staging: row within 16-row group
    const int gran = tid & 15;         // staging: 8-elem chunk

    const float* Asrc = L + ((size_t)bz * N_DIM + (size_t)by * 128) * D_DIM;
    const float* Rbat = R + (size_t)bz * M_DIM * D_DIM;

    // ---- initial stage: A panel (bf16 RNE + norms from SAME rounded values)
    #pragma unroll
    for (int i2 = 0; i2 < 8; ++i2) {
        int row = i2 * 16 + r;
        float4 v0 = ((const float4*)Asrc)[(size_t)row * 32 + gran * 2];
        float4 v1 = ((const float4*)Asrc)[(size_t)row * 32 + gran * 2 + 1];
        bf16x8 p = { (bf16_t)v0.x, (bf16_t)v0.y, (bf16_t)v0.z, (bf16_t)v0.w,
                     (bf16_t)v1.x, (bf16_t)v1.y, (bf16_t)v1.z, (bf16_t)v1.w };
        Als[i2 * 256 + gran * 16 + (r ^ gran)] = p;
        float s = 0.0f;
        #pragma unroll
        for (int j = 0; j < 8; ++j) { float x = (float)p[j]; s = fmaf(x, x, s); }
        s += __shfl_xor(s, 1); s += __shfl_xor(s, 2);
        s += __shfl_xor(s, 4); s += __shfl_xor(s, 8);
        if (gran == 0) nAs[i2 * 16 + r] = s;
    }
    // ---- initial stage: B tile 0 (64 rows)
    {
        const float* Bsrc = Rbat + (size_t)(bxg * NT_TILES) * 64 * D_DIM;
        #pragma unroll
        for (int i2 = 0; i2 < 4; ++i2) {
            int row = i2 * 16 + r;
            float4 v0 = ((const float4*)Bsrc)[(size_t)row * 32 + gran * 2];
            float4 v1 = ((const float4*)Bsrc)[(size_t)row * 32 + gran * 2 + 1];
            bf16x8 p = { (bf16_t)v0.x, (bf16_t)v0.y, (bf16_t)v0.z, (bf16_t)v0.w,
                         (bf16_t)v1.x, (bf16_t)v1.y, (bf16_t)v1.z, (bf16_t)v1.w };
            Bls[i2 * 256 + gran * 16 + (r ^ gran)] = p;
            float s = 0.0f;
            #pragma unroll
            for (int j = 0; j < 8; ++j) { float x = (float)p[j]; s = fmaf(x, x, s); }
            s += __shfl_xor(s, 1); s += __shfl_xor(s, 2);
            s += __shfl_xor(s, 4); s += __shfl_xor(s, 8);
            if (gran == 0) nBs[i2 * 16 + r] = s;
        }
    }
    lgkm_barrier();

    // ---- wave tile bases: 4 waves in 2x2; wave owns 64 rows x 32 cols
    const int wr = wid >> 1;           // 0..1 (row half)
    const int wc = wid & 1;            // 0..1 (col half)
    const int wM = wr * 64;
    const int wN = wc * 32;

    // ---- A fragments into registers (Als dead afterwards): af[tm][s]
    bf16x8 af[2][8];
    #pragma unroll
    for (int s = 0; s < 8; ++s) {
        const int gr = s * 2 + hi;           // 16B k-granule
        #pragma unroll
        for (int tm = 0; tm < 2; ++tm) {
            const int grp = wr * 4 + tm * 2 + g2;
            af[tm][s] = Als[grp * 256 + gr * 16 + (rA ^ gr)];
        }
    }

    // ---- tile loop (8 tiles of 64 cols)
    for (int t = 0; t < NT_TILES; ++t) {
        const int bx = bxg * NT_TILES + t;

        // 1. MFMA on current B tile (8 K-steps of 16, 2 indep chains)
        f32x16 acc[2] = {};
        #pragma unroll
        for (int s = 0; s < 8; ++s) {
            const int gr = s * 2 + hi;
            const bf16x8 bfr = Bls[(wc * 2 + g2) * 256 + gr * 16 + (rA ^ gr)];
            acc[0] = __builtin_amdgcn_mfma_f32_32x32x16_bf16(
                af[0][s], bfr, acc[0], 0, 0, 0);
            acc[1] = __builtin_amdgcn_mfma_f32_32x32x16_bf16(
                af[1][s], bfr, acc[1], 0, 0, 0);
        }

        // 2. prefetch next B tile (f32) into regs BEFORE any stores issue
        //    (vmcnt retires in-order: restage's wait stays counted, stores
        //     never force-drained)
        float4 pf0[4], pf1[4];
        if (t + 1 < NT_TILES) {
            const float* Bsrc = Rbat + (size_t)(bx + 1) * 64 * D_DIM;
            #pragma unroll
            for (int i2 = 0; i2 < 4; ++i2) {
                int row = i2 * 16 + r;
                pf0[i2] = ((const float4*)Bsrc)[(size_t)row * 32 + gran * 2];
                pf1[i2] = ((const float4*)Bsrc)[(size_t)row * 32 + gran * 2 + 1];
            }
        }

        // 3. epilogue + full-line NONTEMPORAL stores
        //    out-row = wM + tm*32 + g*8 + hi*4 + e,  out-col = bx*64 + wN + c32
        const size_t outBase =
            ((size_t)bz * N_DIM + (size_t)by * 128) * M_DIM + (size_t)bx * 64;
        const int col_l = wN + c32;
        const float r2 = nBs[col_l];
        float* ocol = out + outBase + col_l;
        #pragma unroll
        for (int tm = 0; tm < 2; ++tm) {
            #pragma unroll
            for (int g = 0; g < 4; ++g) {
                const int rowb = wM + tm * 32 + g * 8 + hi * 4;
                const f32x4 l2q = *(const f32x4*)&nAs[rowb];
                #pragma unroll
                for (int e = 0; e < 4; ++e) {
                    float d2 = fmaf(-2.0f, acc[tm][g * 4 + e], l2q[e] + r2);
                    d2 = fmaxf(d2, 0.0f);
                    float sq = __builtin_amdgcn_sqrtf(d2);
                    float o = __builtin_amdgcn_rcpf(1.0f + sq);
                    __builtin_nontemporal_store(
                        o, ocol + (size_t)(rowb + e) * M_DIM);
                }
            }
        }

        // 4. restage next B tile from prefetched regs (lgkm-only barriers)
        if (t + 1 < NT_TILES) {
            lgkm_barrier();                    // all waves done reading Bls/nBs
            #pragma unroll
            for (int i2 = 0; i2 < 4; ++i2) {
                bf16x8 p = { (bf16_t)pf0[i2].x, (bf16_t)pf0[i2].y,
                             (bf16_t)pf0[i2].z, (bf16_t)pf0[i2].w,
                             (bf16_t)pf1[i2].x, (bf16_t)pf1[i2].y,
                             (bf16_t)pf1[i2].z, (bf16_t)pf1[i2].w };
                Bls[i2 * 256 + gran * 16 + (r ^ gran)] = p;
                float s = 0.0f;
                #pragma unroll
                for (int j = 0; j < 8; ++j) { float x = (float)p[j]; s = fmaf(x, x, s); }
                s += __shfl_xor(s, 1); s += __shfl_xor(s, 2);
                s += __shfl_xor(s, 4); s += __shfl_xor(s, 8);
                if (gran == 0) nBs[i2 * 16 + r] = s;
            }
            lgkm_barrier();                    // staging visible
        }
    }
}

extern "C" void kernel_launch(void* const* d_in, const int* in_sizes, int n_in,
                              void* d_out, int out_size, void* d_ws, size_t ws_size,
                              hipStream_t stream) {
    const float* L = (const float*)d_in[0];
    const float* R = (const float*)d_in[1];
    float* out = (float*)d_out;

    // 1D grid: w&7 selects XCD (round-robin) == batch; 64 blocks per XCD.
    dim3 grid(512, 1, 1);
    dim3 block(256);
    fused_dist_kernel<<<grid, block, 0, stream>>>(L, R, out);
}